// Round 6
// baseline (186.782 us; speedup 1.0000x reference)
//
#include <hip/hip_runtime.h>
#include <hip/hip_bf16.h>

typedef __hip_bfloat16 bf16;
typedef __attribute__((ext_vector_type(8))) short short8;   // 8 bf16 = one MFMA A/B frag
typedef __attribute__((ext_vector_type(4))) float f32x4;    // MFMA C/D frag

#define MFMA(a, b, c) __builtin_amdgcn_mfma_f32_16x16x32_bf16(a, b, c, 0, 0, 0)

static __device__ __forceinline__ float b2f(unsigned short u) {
  union { unsigned u; float f; } t; t.u = ((unsigned)u) << 16; return t.f;
}
static __device__ __forceinline__ unsigned short f2bf(float f) {
  union { float f; unsigned u; } t; t.f = f;
  unsigned r = t.u + 0x7fffu + ((t.u >> 16) & 1u);   // RNE
  return (unsigned short)(r >> 16);
}
static __device__ __forceinline__ unsigned pack2(float a, float b) {
  return (unsigned)f2bf(a) | ((unsigned)f2bf(b) << 16);
}

// ---- workspace layout (bf16 element offsets) ----
#define KB_OFF   ((size_t)0)          // K  [2048][1024]
#define QB_OFF   ((size_t)2097152)    // Q  [2048][1024]
#define G1_OFF   ((size_t)4194304)    // G1 [2048][1024]
#define G2_OFF   ((size_t)6291456)    // G2 [2048][1024]
#define VT_OFF   ((size_t)8388608)    // V^T [512][2048]
#define WT_BASE  ((size_t)9437184)
#define WTK_OFF  (WT_BASE)                       // [1024][512]
#define WTQ_OFF  (WT_BASE + (size_t)524288)
#define WTG1_OFF (WT_BASE + (size_t)1048576)
#define WTG2_OFF (WT_BASE + (size_t)1572864)
#define WTV_OFF  (WT_BASE + (size_t)2097152)     // [512][512]
// After proj, WT region is dead -> reuse (and extend) for attention partials:
#define NUM0_OFF (WT_BASE)                        // bf16 [2048][512]
#define NUM1_OFF (WT_BASE + (size_t)1048576)      // bf16 [2048][512]
#define NUM2_OFF (WT_BASE + (size_t)2097152)      // bf16 [2048][512]
#define DEN_OFF  (WT_BASE + (size_t)3145728)      // f32 [3][8][2048]
#define VSUM_OFF (WT_BASE + (size_t)3244032)      // f32 [512]
// total ws: 12,682,240 bf16 elems = 25.4 MB

// Transpose + convert W[k][n] fp32 -> Wt[n][k] bf16, all 5 weights in one launch.
__global__ __launch_bounds__(256)
void wtrans_kernel(const float* __restrict__ WK, const float* __restrict__ WQ,
                   const float* __restrict__ WG1, const float* __restrict__ WG2,
                   const float* __restrict__ WV, bf16* __restrict__ ws)
{
  __shared__ float T[32][33];
  const float* W; unsigned short* Wt; int N;
  switch (blockIdx.z) {
    case 0:  W = WK;  Wt = (unsigned short*)(ws + WTK_OFF);  N = 1024; break;
    case 1:  W = WQ;  Wt = (unsigned short*)(ws + WTQ_OFF);  N = 1024; break;
    case 2:  W = WG1; Wt = (unsigned short*)(ws + WTG1_OFF); N = 1024; break;
    case 3:  W = WG2; Wt = (unsigned short*)(ws + WTG2_OFF); N = 1024; break;
    default: W = WV;  Wt = (unsigned short*)(ws + WTV_OFF);  N = 512;  break;
  }
  int n0 = blockIdx.x * 32, k0 = blockIdx.y * 32;
  if (n0 >= N) return;
  int tid = threadIdx.x;
  int kk = tid >> 3, nn = (tid & 7) * 4;
  float4 v = *(const float4*)(W + (size_t)(k0 + kk) * N + n0 + nn);
  T[kk][nn] = v.x; T[kk][nn + 1] = v.y; T[kk][nn + 2] = v.z; T[kk][nn + 3] = v.w;
  __syncthreads();
  int n2 = tid >> 3, k2 = (tid & 7) * 4;
  uint2 pw;
  pw.x = pack2(T[k2][n2],     T[k2 + 1][n2]);
  pw.y = pack2(T[k2 + 2][n2], T[k2 + 3][n2]);
  *(uint2*)(Wt + (size_t)(n0 + n2) * 512 + k0 + k2) = pw;
}

// Batched MFMA projection GEMM (verified round 4).
__global__ __launch_bounds__(256)
void proj_mfma_kernel(const float* __restrict__ fa, const float* __restrict__ fp,
                      const float* __restrict__ sa, const float* __restrict__ sp,
                      const float* __restrict__ bKp, const float* __restrict__ bQp,
                      const float* __restrict__ bG1p, const float* __restrict__ bG2p,
                      const float* __restrict__ bVp, bf16* __restrict__ ws)
{
  __shared__ short Xs[128][40];
  __shared__ short Wsh[128][40];
  const float* X; const unsigned short* Wt; const float* bias; unsigned short* C;
  int N; bool trans = false;
  switch (blockIdx.z) {
    case 0:  X = fa; Wt = (const unsigned short*)(ws + WTK_OFF);  bias = bKp;  C = (unsigned short*)(ws + KB_OFF); N = 1024; break;
    case 1:  X = sa; Wt = (const unsigned short*)(ws + WTQ_OFF);  bias = bQp;  C = (unsigned short*)(ws + QB_OFF); N = 1024; break;
    case 2:  X = fp; Wt = (const unsigned short*)(ws + WTG1_OFF); bias = bG1p; C = (unsigned short*)(ws + G1_OFF); N = 1024; break;
    case 3:  X = sp; Wt = (const unsigned short*)(ws + WTG2_OFF); bias = bG2p; C = (unsigned short*)(ws + G2_OFF); N = 1024; break;
    default: X = fa; Wt = (const unsigned short*)(ws + WTV_OFF);  bias = bVp;  C = (unsigned short*)(ws + VT_OFF); N = 512; trans = true; break;
  }
  const int n0 = blockIdx.x * 128;
  if (n0 >= N) return;
  const int m0 = blockIdx.y * 128;
  const int tid = threadIdx.x;
  const int w = tid >> 6, l = tid & 63, l15 = l & 15, l4 = l >> 4;
  const int wm = (w & 1) * 64, wn = (w >> 1) * 64;
  const int srow = tid >> 1, shalf = (tid & 1) * 16;

  const float* xp = X + (size_t)(m0 + srow) * 512 + shalf;
  const unsigned short* wp = Wt + (size_t)(n0 + srow) * 512 + shalf;

  const f32x4 zero = {0.f, 0.f, 0.f, 0.f};
  f32x4 acc[4][4];
#pragma unroll
  for (int i = 0; i < 4; ++i)
#pragma unroll
    for (int j = 0; j < 4; ++j) acc[i][j] = zero;

  float4 px[4]; uint4 pw0, pw1;
  auto ldg = [&](int kc) {
    px[0] = *(const float4*)(xp + kc);
    px[1] = *(const float4*)(xp + kc + 4);
    px[2] = *(const float4*)(xp + kc + 8);
    px[3] = *(const float4*)(xp + kc + 12);
    pw0 = *(const uint4*)(wp + kc);
    pw1 = *(const uint4*)(wp + kc + 8);
  };
  ldg(0);

  for (int kc = 0; kc < 512; kc += 32) {
    __syncthreads();
    uint4 xa, xb;
    xa.x = pack2(px[0].x, px[0].y); xa.y = pack2(px[0].z, px[0].w);
    xa.z = pack2(px[1].x, px[1].y); xa.w = pack2(px[1].z, px[1].w);
    xb.x = pack2(px[2].x, px[2].y); xb.y = pack2(px[2].z, px[2].w);
    xb.z = pack2(px[3].x, px[3].y); xb.w = pack2(px[3].z, px[3].w);
    *(uint4*)&Xs[srow][shalf]      = xa;
    *(uint4*)&Xs[srow][shalf + 8]  = xb;
    *(uint4*)&Wsh[srow][shalf]     = pw0;
    *(uint4*)&Wsh[srow][shalf + 8] = pw1;
    __syncthreads();
    if (kc + 32 < 512) ldg(kc + 32);

    short8 xf[4], wf[4];
#pragma unroll
    for (int t = 0; t < 4; ++t) {
      xf[t] = *(const short8*)&Xs[wm + t * 16 + l15][l4 * 8];
      wf[t] = *(const short8*)&Wsh[wn + t * 16 + l15][l4 * 8];
    }
    if (!trans) {
#pragma unroll
      for (int i = 0; i < 4; ++i)
#pragma unroll
        for (int j = 0; j < 4; ++j)
          acc[i][j] = MFMA(wf[i], xf[j], acc[i][j]);   // D[n][m]
    } else {
#pragma unroll
      for (int i = 0; i < 4; ++i)
#pragma unroll
        for (int j = 0; j < 4; ++j)
          acc[i][j] = MFMA(xf[i], wf[j], acc[i][j]);   // D[m][n]
    }
  }

  if (!trans) {
#pragma unroll
    for (int tn = 0; tn < 4; ++tn) {
      float4 b4 = *(const float4*)(bias + n0 + wn + tn * 16 + l4 * 4);
#pragma unroll
      for (int tm = 0; tm < 4; ++tm) {
        uint2 pw;
        pw.x = pack2(acc[tn][tm][0] + b4.x, acc[tn][tm][1] + b4.y);
        pw.y = pack2(acc[tn][tm][2] + b4.z, acc[tn][tm][3] + b4.w);
        *(uint2*)(C + (size_t)(m0 + wm + tm * 16 + l15) * N + n0 + wn + tn * 16 + l4 * 4) = pw;
      }
    }
  } else {
#pragma unroll
    for (int tn = 0; tn < 4; ++tn) {
      float bn = bias[n0 + wn + tn * 16 + l15];
#pragma unroll
      for (int tm = 0; tm < 4; ++tm) {
        uint2 pw;
        pw.x = pack2(acc[tm][tn][0] + bn, acc[tm][tn][1] + bn);
        pw.y = pack2(acc[tm][tn][2] + bn, acc[tm][tn][3] + bn);
        *(uint2*)(C + (size_t)(n0 + wn + tn * 16 + l15) * 2048 + m0 + wm + tm * 16 + l4 * 4) = pw;
      }
    }
  }
}

// Vsum[c] = sum_n V[n][c] (read V^T rows). 8 blocks x 256 thr; 4 thr per c.
__global__ __launch_bounds__(256)
void vsum_kernel(const bf16* __restrict__ ws_vt, float* __restrict__ vs)
{
  int tid = threadIdx.x;
  int c = blockIdx.x * 64 + (tid >> 2);
  int q = tid & 3;
  const unsigned short* vp = (const unsigned short*)ws_vt + (size_t)c * 2048 + q * 512;
  float s = 0.f;
  for (int i = 0; i < 512; i += 8) {
    short8 v = *(const short8*)(vp + i);
#pragma unroll
    for (int j = 0; j < 8; ++j) s += b2f((unsigned short)v[j]);
  }
  s += __shfl_xor(s, 1, 64);
  s += __shfl_xor(s, 2, 64);
  if (q == 0) vs[c] = s;
}

// MFMA fused attention, n-split=3 (grid 768 = 3 blocks/CU, 3 waves/SIMD).
// PV computed as O^T = V^T · P^T: A-frag = V^T rows (b128), B-frag = P row-major
// (2x b128 — replaces 16 scalar u16 reads of round 5). P' = exp(x)-1 ~= x+x^2/2.
// Partial numerator excludes sumV (combine adds Vsum[c]); denom via ones-A MFMA.
__global__ __launch_bounds__(256)
void attn_mfma_kernel(const bf16* __restrict__ Kb, const bf16* __restrict__ G1b,
                      const bf16* __restrict__ Vtg, const bf16* __restrict__ Qb,
                      const bf16* __restrict__ G2b, bf16* __restrict__ ws)
{
  __shared__ short Ks[64][136];    // stride 272B: b128 frag reads bank-balanced
  __shared__ short G1s[64][136];
  __shared__ short Vts[64][72];    // V^T[j][n], stride 144B
  __shared__ short Pr[4][16][72];  // per-wave P row-major [m][n], stride 144B
  // total LDS = 17408*2 + 9216 + 9216 = 53248 B -> 3 blocks/CU

  const int tid = threadIdx.x;
  const int w   = tid >> 6;
  const int l   = tid & 63;
  const int l15 = l & 15;
  const int l4  = l >> 4;
  const int h   = blockIdx.y;
  const int m0  = blockIdx.x * 64;
  const int split = blockIdx.z;

  // ---- persistent Q/G2 A-fragments (row m0+w*16+l15) ----
  short8 qf[4], gf[4];
  {
    const size_t ro = (size_t)(m0 + w * 16 + l15) * 1024 + h * 128 + l4 * 8;
#pragma unroll
    for (int kk = 0; kk < 4; ++kk) {
      qf[kk] = *(const short8*)(Qb + ro + kk * 32);
      gf[kk] = *(const short8*)(G2b + ro + kk * 32);
    }
  }
  // ---- row norms -> per-lane sc (row l15); broadcast to s4[r] via shuffles ----
  float s4[4];
  {
    float sq = 0.f, sg = 0.f;
#pragma unroll
    for (int kk = 0; kk < 4; ++kk)
#pragma unroll
      for (int j = 0; j < 8; ++j) {
        float q = b2f((unsigned short)qf[kk][j]);
        float g = b2f((unsigned short)gf[kk][j]);
        sq += q * q; sg += g * g;
      }
    sq += __shfl_xor(sq, 16, 64); sq += __shfl_xor(sq, 32, 64);
    sg += __shfl_xor(sg, 16, 64); sg += __shfl_xor(sg, 32, 64);
    float sc = rsqrtf(sq) * rsqrtf(sg) * (1.0f / 16384.0f);
    s4[0] = __shfl(sc, l4 * 4 + 0, 64);
    s4[1] = __shfl(sc, l4 * 4 + 1, 64);
    s4[2] = __shfl(sc, l4 * 4 + 2, 64);
    s4[3] = __shfl(sc, l4 * 4 + 3, 64);
  }

  const int r0 = tid >> 3, c0 = (tid & 7) * 16;   // K/G1 staging map
  const int jv = tid >> 2, nv = (tid & 3) * 16;   // Vt staging map

  short8 pk[4], pg[4], pv0, pv1;
  auto load_tile = [&](int nt) {       // nt in global 64-units
    const int n0 = nt * 64;
    const bf16* kp = Kb  + (size_t)(n0 + r0) * 1024 + h * 128 + c0;
    const bf16* gp = G1b + (size_t)(n0 + r0) * 1024 + h * 128 + c0;
    pk[0] = *(const short8*)(kp);
    pk[1] = *(const short8*)(kp + 8);
    pk[2] = *(const short8*)(kp + 32 * 1024);
    pk[3] = *(const short8*)(kp + 32 * 1024 + 8);
    pg[0] = *(const short8*)(gp);
    pg[1] = *(const short8*)(gp + 8);
    pg[2] = *(const short8*)(gp + 32 * 1024);
    pg[3] = *(const short8*)(gp + 32 * 1024 + 8);
    const bf16* vp = Vtg + (size_t)(h * 64 + jv) * 2048 + n0 + nv;
    pv0 = *(const short8*)(vp);
    pv1 = *(const short8*)(vp + 8);
  };
  const int ntbase = split * 11;                 // 0, 11, 22
  const int ntcnt  = (split == 2) ? 10 : 11;     // tiles 0..10 / 11..21 / 22..31
  load_tile(ntbase);

  const f32x4 zero = {0.f, 0.f, 0.f, 0.f};
  f32x4 accO[4], accD = zero;
#pragma unroll
  for (int t = 0; t < 4; ++t) accO[t] = zero;

  short8 ones;
#pragma unroll
  for (int j = 0; j < 8; ++j) ones[j] = (short)0x3F80;  // bf16 1.0

  for (int nt = 0; nt < ntcnt; ++nt) {
    __syncthreads();
    *(short8*)&Ks[r0][c0]           = pk[0];
    *(short8*)&Ks[r0][c0 + 8]       = pk[1];
    *(short8*)&Ks[r0 + 32][c0]      = pk[2];
    *(short8*)&Ks[r0 + 32][c0 + 8]  = pk[3];
    *(short8*)&G1s[r0][c0]          = pg[0];
    *(short8*)&G1s[r0][c0 + 8]      = pg[1];
    *(short8*)&G1s[r0 + 32][c0]     = pg[2];
    *(short8*)&G1s[r0 + 32][c0 + 8] = pg[3];
    *(short8*)&Vts[jv][nv]          = pv0;
    *(short8*)&Vts[jv][nv + 8]      = pv1;
    __syncthreads();
    if (nt + 1 < ntcnt) load_tile(ntbase + nt + 1);   // prefetch overlaps compute

    // ---- scores: SA = Q·K^T, SG = G2·G1^T; lane holds (m=l4*4+r, n=t*16+l15) ----
    f32x4 sa[4], sg2[4];
#pragma unroll
    for (int t = 0; t < 4; ++t) { sa[t] = zero; sg2[t] = zero; }
#pragma unroll
    for (int t = 0; t < 4; ++t) {
#pragma unroll
      for (int kk = 0; kk < 4; ++kk) {
        short8 kbf = *(const short8*)&Ks[t * 16 + l15][kk * 32 + l4 * 8];
        sa[t]  = MFMA(qf[kk], kbf, sa[t]);
        short8 gbf = *(const short8*)&G1s[t * 16 + l15][kk * 32 + l4 * 8];
        sg2[t] = MFMA(gf[kk], gbf, sg2[t]);
      }
    }
    // ---- P' = x + x^2/2, bf16, row-major per-wave scratch [m][n] ----
#pragma unroll
    for (int t = 0; t < 4; ++t) {
      float x0 = sa[t][0] * sg2[t][0] * s4[0];
      float x1 = sa[t][1] * sg2[t][1] * s4[1];
      float x2 = sa[t][2] * sg2[t][2] * s4[2];
      float x3 = sa[t][3] * sg2[t][3] * s4[3];
      Pr[w][l4 * 4 + 0][t * 16 + l15] = (short)f2bf(__builtin_fmaf(0.5f * x0, x0, x0));
      Pr[w][l4 * 4 + 1][t * 16 + l15] = (short)f2bf(__builtin_fmaf(0.5f * x1, x1, x1));
      Pr[w][l4 * 4 + 2][t * 16 + l15] = (short)f2bf(__builtin_fmaf(0.5f * x2, x2, x2));
      Pr[w][l4 * 4 + 3][t * 16 + l15] = (short)f2bf(__builtin_fmaf(0.5f * x3, x3, x3));
    }
    // ---- PV as O^T = V^T·P^T; denom via ones-A MFMA (same-wave LDS RAW) ----
#pragma unroll
    for (int ks = 0; ks < 2; ++ks) {
      short8 pf = *(const short8*)&Pr[w][l15][ks * 32 + l4 * 8];   // B[k=n][m=l15]
      accD = MFMA(ones, pf, accD);                                 // D[*][m] = sum_n P[m][n]
#pragma unroll
      for (int jt = 0; jt < 4; ++jt) {
        short8 va = *(const short8*)&Vts[jt * 16 + l15][ks * 32 + l4 * 8];  // A[j][n]
        accO[jt] = MFMA(va, pf, accO[jt]);                         // D[j=l4*4+r][m=l15]
      }
    }
  }

  // ---- write partials: num (bf16, packed j-quads) + den (f32) ----
  unsigned short* num = (unsigned short*)(ws +
      (split == 0 ? NUM0_OFF : split == 1 ? NUM1_OFF : NUM2_OFF));
  float* den = (float*)(ws + DEN_OFF);
  if (l4 == 0)
    den[((size_t)split * 8 + h) * 2048 + m0 + w * 16 + l15] = accD[0];
#pragma unroll
  for (int jt = 0; jt < 4; ++jt) {
    uint2 pw;
    pw.x = pack2(accO[jt][0], accO[jt][1]);
    pw.y = pack2(accO[jt][2], accO[jt][3]);
    *(uint2*)(num + (size_t)(m0 + w * 16 + l15) * 512 + h * 64 + jt * 16 + l4 * 4) = pw;
  }
}

// out[m][c] = (Vsum[c] + num0+num1+num2) / (2048 + den0+den1+den2), c = h*64+j
__global__ __launch_bounds__(256)
void combine_kernel(const bf16* __restrict__ ws, float* __restrict__ out)
{
  const unsigned short* num0 = (const unsigned short*)(ws + NUM0_OFF);
  const unsigned short* num1 = (const unsigned short*)(ws + NUM1_OFF);
  const unsigned short* num2 = (const unsigned short*)(ws + NUM2_OFF);
  const float* den = (const float*)(ws + DEN_OFF);
  const float* vs  = (const float*)(ws + VSUM_OFF);
  int idx = blockIdx.x * 256 + threadIdx.x;
  int m = idx >> 9, c = idx & 511, h = c >> 6;
  float d = 2048.0f + den[(size_t)h * 2048 + m]
                    + den[(size_t)(8 + h) * 2048 + m]
                    + den[(size_t)(16 + h) * 2048 + m];
  float n = vs[c] + b2f(num0[idx]) + b2f(num1[idx]) + b2f(num2[idx]);
  out[idx] = n / d;
}

extern "C" void kernel_launch(void* const* d_in, const int* in_sizes, int n_in,
                              void* d_out, int out_size, void* d_ws, size_t ws_size,
                              hipStream_t stream) {
  const float* first_app  = (const float*)d_in[0];
  const float* first_pos  = (const float*)d_in[1];
  const float* second_app = (const float*)d_in[2];
  const float* second_pos = (const float*)d_in[3];
  const float* WK  = (const float*)d_in[4];
  const float* bK  = (const float*)d_in[5];
  const float* WQ  = (const float*)d_in[6];
  const float* bQ  = (const float*)d_in[7];
  const float* WV  = (const float*)d_in[8];
  const float* bV  = (const float*)d_in[9];
  const float* WG1 = (const float*)d_in[10];
  const float* bG1 = (const float*)d_in[11];
  const float* WG2 = (const float*)d_in[12];
  const float* bG2 = (const float*)d_in[13];

  bf16* ws = (bf16*)d_ws;

  wtrans_kernel<<<dim3(32, 16, 5), 256, 0, stream>>>(WK, WQ, WG1, WG2, WV, ws);
  proj_mfma_kernel<<<dim3(8, 16, 5), 256, 0, stream>>>(
      first_app, first_pos, second_app, second_pos, bK, bQ, bG1, bG2, bV, ws);
  vsum_kernel<<<dim3(8), 256, 0, stream>>>(ws + VT_OFF, (float*)(ws + VSUM_OFF));
  attn_mfma_kernel<<<dim3(32, 8, 3), 256, 0, stream>>>(
      ws + KB_OFF, ws + G1_OFF, ws + VT_OFF, ws + QB_OFF, ws + G2_OFF, ws);
  combine_kernel<<<dim3(4096), 256, 0, stream>>>(ws, (float*)d_out);
}